// Round 7
// baseline (487.091 us; speedup 1.0000x reference)
//
#include <hip/hip_runtime.h>

#define N_NODES 50000
#define N_EDGES 800000
#define D_IN 128
#define HIDDEN 64
#define N_CLASSES 2
#define NBUK 782        // ceil(50000/64) buckets of 64 nodes
#define NBUK_P 784      // padded stride (bhist rows)
#define NBLK 782        // edge-chunk blocks: 782*1024 >= 800000
#define NBLK_P 784      // padded stride (excT rows)

typedef _Float16 half4v __attribute__((ext_vector_type(4)));

// ---------------- phase 1: per-chunk LDS histogram over dst buckets ----------------

__global__ __launch_bounds__(256) void k_hist(const int4* __restrict__ dst4,
                                              int* __restrict__ bhist) {
    __shared__ int hist[NBUK];
    int t = threadIdx.x;
    for (int i = t; i < NBUK; i += 256) hist[i] = 0;
    __syncthreads();
    int idx = blockIdx.x * 256 + t;
    if (idx < N_EDGES / 4) {
        int4 d = dst4[idx];
        atomicAdd(&hist[d.x >> 6], 1);
        atomicAdd(&hist[d.y >> 6], 1);
        atomicAdd(&hist[d.z >> 6], 1);
        atomicAdd(&hist[d.w >> 6], 1);
    }
    __syncthreads();
    for (int i = t; i < NBUK; i += 256) bhist[blockIdx.x * NBUK_P + i] = hist[i];
}

// ---------------- phase 2: column scan over chunks; excT transposed (coalesced writes) ----------------

__global__ __launch_bounds__(256) void k_colscan(const int* __restrict__ bhist,
                                                 int* __restrict__ excT,
                                                 int* __restrict__ colsum) {
    __shared__ int part[256];
    int b = blockIdx.x;   // bucket
    int t = threadIdx.x;
    int v[4];
    int s = 0;
#pragma unroll
    for (int i = 0; i < 4; i++) {
        int blk = t * 4 + i;
        v[i] = (blk < NBLK) ? bhist[blk * NBUK_P + b] : 0;
        s += v[i];
    }
    part[t] = s;
    __syncthreads();
    for (int off = 1; off < 256; off <<= 1) {
        int p = (t >= off) ? part[t - off] : 0;
        __syncthreads();
        part[t] += p;
        __syncthreads();
    }
    int run = (t == 0) ? 0 : part[t - 1];
#pragma unroll
    for (int i = 0; i < 4; i++) {
        int blk = t * 4 + i;
        if (blk < NBLK) excT[b * NBLK_P + blk] = run;
        run += v[i];
    }
    if (t == 255) colsum[b] = run;
}

// ---------------- phase 3: scan 782 bucket totals -> bucket_off ----------------

__global__ __launch_bounds__(256) void k_bucket_scan(const int* __restrict__ colsum,
                                                     int* __restrict__ bucket_off) {
    __shared__ int part[256];
    int t = threadIdx.x;
    int v[4];
    int s = 0;
#pragma unroll
    for (int i = 0; i < 4; i++) {
        int idx = t * 4 + i;
        v[i] = (idx < NBUK) ? colsum[idx] : 0;
        s += v[i];
    }
    part[t] = s;
    __syncthreads();
    for (int off = 1; off < 256; off <<= 1) {
        int p = (t >= off) ? part[t - off] : 0;
        __syncthreads();
        part[t] += p;
        __syncthreads();
    }
    int run = (t == 0) ? 0 : part[t - 1];
#pragma unroll
    for (int i = 0; i < 4; i++) {
        int idx = t * 4 + i;
        if (idx < NBUK) { bucket_off[idx] = run; run += v[i]; }
        else if (idx == NBUK) bucket_off[idx] = run;  // == N_EDGES
    }
}

// ---------------- phase 4: deterministic scatter of packed records ----------------
// pk = (src << 7) | (dst & 63); src < 50000 < 2^17, 7-bit field leaves room for dummy d=64.

__global__ __launch_bounds__(256) void k_binA2(const int4* __restrict__ src4,
                                               const int4* __restrict__ dst4,
                                               const int* __restrict__ excT,
                                               const int* __restrict__ bucket_off,
                                               int* __restrict__ ebin) {
    __shared__ int cur[NBUK];
    int t = threadIdx.x;
    for (int i = t; i < NBUK; i += 256)
        cur[i] = bucket_off[i] + excT[i * NBLK_P + blockIdx.x];
    __syncthreads();
    int idx = blockIdx.x * 256 + t;
    if (idx < N_EDGES / 4) {
        int4 s = src4[idx];
        int4 d = dst4[idx];
        int p0 = atomicAdd(&cur[d.x >> 6], 1);
        int p1 = atomicAdd(&cur[d.y >> 6], 1);
        int p2 = atomicAdd(&cur[d.z >> 6], 1);
        int p3 = atomicAdd(&cur[d.w >> 6], 1);
        ebin[p0] = (s.x << 7) | (d.x & 63);
        ebin[p1] = (s.y << 7) | (d.y & 63);
        ebin[p2] = (s.z << 7) | (d.z & 63);
        ebin[p3] = (s.w << 7) | (d.w & 63);
    }
}

// ---------------- per-bucket degree -> dinv (LDS count, no scan needed) ----------------

__global__ __launch_bounds__(256) void k_deg_dinv(const int* __restrict__ ebin,
                                                  const int* __restrict__ bucket_off,
                                                  float* __restrict__ dinv) {
    __shared__ int cnt[64];
    int b = blockIdx.x;
    int t = threadIdx.x;
    if (t < 64) cnt[t] = 0;
    __syncthreads();
    int beg = bucket_off[b], end = bucket_off[b + 1];
    for (int i = beg + t; i < end; i += 256) atomicAdd(&cnt[ebin[i] & 63], 1);
    __syncthreads();
    if (t < 64) {
        int node = b * 64 + t;
        if (node < N_NODES) dinv[node] = rsqrtf((float)(cnt[t] + 1));  // +1 self-loop
    }
}

// ---------------- GEMM1: hs = (x @ W1) * dinv[row], stored fp16 ----------------

__device__ inline void fma4(float4& acc, float s, const float4& w) {
    acc.x = fmaf(s, w.x, acc.x);
    acc.y = fmaf(s, w.y, acc.y);
    acc.z = fmaf(s, w.z, acc.z);
    acc.w = fmaf(s, w.w, acc.w);
}

__global__ __launch_bounds__(256) void k_gemm1(
    const float* __restrict__ x, const float* __restrict__ W1,
    const float* __restrict__ dinv, _Float16* __restrict__ hs)
{
    __shared__ float Ws[D_IN * HIDDEN];  // [k][col] 32KB
    __shared__ float xs[64 * D_IN];      // [row][k^swz] 32KB
    const int tid = threadIdx.x;
    const int row0 = blockIdx.x * 64;

    const float4* W4 = (const float4*)W1;
    float4* Ws4 = (float4*)Ws;
    for (int i = tid; i < D_IN * HIDDEN / 4; i += 256) Ws4[i] = W4[i];

    for (int i = tid; i < 64 * D_IN / 4; i += 256) {
        int r = i >> 5;
        int k4 = (i & 31) << 2;
        float4 v = make_float4(0.f, 0.f, 0.f, 0.f);
        int grow = row0 + r;
        if (grow < N_NODES) v = *(const float4*)&x[grow * D_IN + k4];
        int sw = ((r >> 2) & 1) << 4;
        *(float4*)&xs[r * D_IN + (k4 ^ sw)] = v;
    }
    __syncthreads();

    const int c4 = (tid & 15) * 4;
    const int r4 = (tid >> 4) * 4;
    float4 acc[4];
#pragma unroll
    for (int j = 0; j < 4; j++) acc[j] = make_float4(0.f, 0.f, 0.f, 0.f);

    for (int k = 0; k < D_IN; k += 4) {
        float4 w0 = *(const float4*)&Ws[(k + 0) * HIDDEN + c4];
        float4 w1 = *(const float4*)&Ws[(k + 1) * HIDDEN + c4];
        float4 w2 = *(const float4*)&Ws[(k + 2) * HIDDEN + c4];
        float4 w3 = *(const float4*)&Ws[(k + 3) * HIDDEN + c4];
        float4 a[4];
#pragma unroll
        for (int j = 0; j < 4; j++) {
            int r = r4 + j;
            int sw = ((r >> 2) & 1) << 4;
            a[j] = *(const float4*)&xs[r * D_IN + (k ^ sw)];
        }
#pragma unroll
        for (int j = 0; j < 4; j++) {
            fma4(acc[j], a[j].x, w0);
            fma4(acc[j], a[j].y, w1);
            fma4(acc[j], a[j].z, w2);
            fma4(acc[j], a[j].w, w3);
        }
    }

#pragma unroll
    for (int j = 0; j < 4; j++) {
        int grow = row0 + r4 + j;
        if (grow < N_NODES) {
            float di = dinv[grow];
            half4v hv;
            hv.x = (_Float16)(acc[j].x * di);
            hv.y = (_Float16)(acc[j].y * di);
            hv.z = (_Float16)(acc[j].z * di);
            hv.w = (_Float16)(acc[j].w * di);
            *(half4v*)&hs[grow * HIDDEN + c4] = hv;
        }
    }
}

// ---------------- fused agg1 + relu + layer2: block per bucket, LDS accumulator ----------------
// acc[d][f] += hs[src][f] (plain sum — weights folded into hs). Row 64 = dummy pad.
__global__ __launch_bounds__(256) void k_agg1(
    const _Float16* __restrict__ hs, const int* __restrict__ ebin,
    const int* __restrict__ bucket_off, const float* __restrict__ dinv,
    const float* __restrict__ b1, const float* __restrict__ W2,
    float* __restrict__ zs)
{
    __shared__ float acc[65 * 64];  // 16.25 KB
    const int b = blockIdx.x;
    const int tid = threadIdx.x;
    const int wave = tid >> 6;
    const int lane = tid & 63;

    for (int i = tid; i < 65 * 64 / 4; i += 256)
        ((float4*)acc)[i] = make_float4(0.f, 0.f, 0.f, 0.f);
    __syncthreads();

    const int beg = bucket_off[b];
    const int end = bucket_off[b + 1];

    for (int base = beg + wave * 64; base < end; base += 256) {
        int m = end - base;
        int live = m < 64 ? m : 64;
        int pk = 64;  // dummy: src=0 (valid mem), d=64 (trash row)
        if (lane < live) pk = ebin[base + lane];
        int n4 = (live + 3) & ~3;
        for (int e = 0; e < n4; e += 4) {
            int p0 = __builtin_amdgcn_readlane(pk, e + 0);
            int p1 = __builtin_amdgcn_readlane(pk, e + 1);
            int p2 = __builtin_amdgcn_readlane(pk, e + 2);
            int p3 = __builtin_amdgcn_readlane(pk, e + 3);
            float v0 = (float)hs[(p0 >> 7) * HIDDEN + lane];
            float v1 = (float)hs[(p1 >> 7) * HIDDEN + lane];
            float v2 = (float)hs[(p2 >> 7) * HIDDEN + lane];
            float v3 = (float)hs[(p3 >> 7) * HIDDEN + lane];
            atomicAdd(&acc[(p0 & 127) * 64 + lane], v0);
            atomicAdd(&acc[(p1 & 127) * 64 + lane], v1);
            atomicAdd(&acc[(p2 & 127) * 64 + lane], v2);
            atomicAdd(&acc[(p3 & 127) * 64 + lane], v3);
        }
    }
    __syncthreads();

    // epilogue: 4 waves x 16 nodes; y = relu(di*(acc+self)+b1); zs = (y@W2)*di
    float bb = b1[lane];
    float w20 = W2[lane * N_CLASSES + 0];
    float w21 = W2[lane * N_CLASSES + 1];
#pragma unroll 1
    for (int i = 0; i < 16; i++) {
        int nloc = wave * 16 + i;
        int node = b * 64 + nloc;
        if (node >= N_NODES) break;
        float di = dinv[node];
        float self = (float)hs[node * HIDDEN + lane];
        float a = (acc[nloc * 64 + lane] + self) * di;
        float y = fmaxf(a + bb, 0.0f);
        float p0 = y * w20;
        float p1 = y * w21;
#pragma unroll
        for (int off = 32; off > 0; off >>= 1) {
            p0 += __shfl_down(p0, off, 64);
            p1 += __shfl_down(p1, off, 64);
        }
        if (lane == 0) {
            zs[node * 2 + 0] = p0 * di;
            zs[node * 2 + 1] = p1 * di;
        }
    }
}

// ---------------- agg2: block per bucket, 2-wide LDS accumulator; writes final out ----------------

__global__ __launch_bounds__(256) void k_agg2(
    const float* __restrict__ zs, const int* __restrict__ ebin,
    const int* __restrict__ bucket_off, const float* __restrict__ dinv,
    const float* __restrict__ b2, float* __restrict__ out)
{
    __shared__ float acc[128];
    int b = blockIdx.x;
    int t = threadIdx.x;
    if (t < 128) acc[t] = 0.f;
    __syncthreads();
    int beg = bucket_off[b], end = bucket_off[b + 1];
    for (int i = beg + t; i < end; i += 256) {
        int p = ebin[i];
        float2 v = *(const float2*)&zs[(p >> 7) * 2];
        int d = p & 63;
        atomicAdd(&acc[d * 2 + 0], v.x);
        atomicAdd(&acc[d * 2 + 1], v.y);
    }
    __syncthreads();
    if (t < 64) {
        int node = b * 64 + t;
        if (node < N_NODES) {
            float di = dinv[node];
            float2 zv = *(const float2*)&zs[node * 2];
            float2 o;
            o.x = fmaf(di, acc[t * 2 + 0] + zv.x, b2[0]);
            o.y = fmaf(di, acc[t * 2 + 1] + zv.y, b2[1]);
            *(float2*)&out[node * 2] = o;
        }
    }
}

// ---------------- launch ----------------

extern "C" void kernel_launch(void* const* d_in, const int* in_sizes, int n_in,
                              void* d_out, int out_size, void* d_ws, size_t ws_size,
                              hipStream_t stream) {
    const float* x  = (const float*)d_in[0];
    const int* ei   = (const int*)d_in[1];
    const float* W1 = (const float*)d_in[2];
    const float* b1 = (const float*)d_in[3];
    const float* W2 = (const float*)d_in[4];
    const float* b2 = (const float*)d_in[5];
    float* out = (float*)d_out;

    const int* src = ei;
    const int* dst = ei + N_EDGES;

    // workspace layout (4-byte units), ~15.1 MB
    int*      bucket_off = (int*)d_ws;                   // [0, 1024)      783 used
    int*      colsum     = (int*)d_ws + 1024;            // [1024, 2048)
    float*    dinv       = (float*)d_ws + 2048;          // [2048, 52224)
    int*      bhist      = (int*)d_ws + 52224;           // 782*784 = 613088 -> pad 665344
    int*      excT       = (int*)d_ws + 665344;          // 782*784 -> pad 1278464
    int*      ebin       = (int*)d_ws + 1278464;         // 800000 packed ints
    _Float16* hs         = (_Float16*)((int*)d_ws + 2078464);  // 3.2M halves (8B aligned)
    float*    zs         = (float*)d_ws + 3678464;       // 100k floats

    k_hist<<<NBLK, 256, 0, stream>>>((const int4*)dst, bhist);
    k_colscan<<<NBUK, 256, 0, stream>>>(bhist, excT, colsum);
    k_bucket_scan<<<1, 256, 0, stream>>>(colsum, bucket_off);
    k_binA2<<<NBLK, 256, 0, stream>>>((const int4*)src, (const int4*)dst, excT, bucket_off, ebin);
    k_deg_dinv<<<NBUK, 256, 0, stream>>>(ebin, bucket_off, dinv);
    k_gemm1<<<(N_NODES + 63) / 64, 256, 0, stream>>>(x, W1, dinv, hs);
    k_agg1<<<NBUK, 256, 0, stream>>>(hs, ebin, bucket_off, dinv, b1, W2, zs);
    k_agg2<<<NBUK, 256, 0, stream>>>(zs, ebin, bucket_off, dinv, b2, out);
}

// Round 8
// 164.861 us; speedup vs baseline: 2.9546x; 2.9546x over previous
//
#include <hip/hip_runtime.h>

#define N_NODES 50000
#define N_EDGES 800000
#define D_IN 128
#define HIDDEN 64
#define N_CLASSES 2
#define NBUK 782        // ceil(50000/64) buckets of 64 nodes
#define NBUK_P 784      // padded stride (bhist rows)
#define NBLK 782        // edge-chunk blocks: 782*1024 >= 800000
#define NBLK_P 784      // padded stride (excT rows)

typedef _Float16 half4v __attribute__((ext_vector_type(4)));

// ---------------- phase 1: per-chunk LDS histogram over dst buckets ----------------

__global__ __launch_bounds__(256) void k_hist(const int4* __restrict__ dst4,
                                              int* __restrict__ bhist) {
    __shared__ int hist[NBUK];
    int t = threadIdx.x;
    for (int i = t; i < NBUK; i += 256) hist[i] = 0;
    __syncthreads();
    int idx = blockIdx.x * 256 + t;
    if (idx < N_EDGES / 4) {
        int4 d = dst4[idx];
        atomicAdd(&hist[d.x >> 6], 1);
        atomicAdd(&hist[d.y >> 6], 1);
        atomicAdd(&hist[d.z >> 6], 1);
        atomicAdd(&hist[d.w >> 6], 1);
    }
    __syncthreads();
    for (int i = t; i < NBUK; i += 256) bhist[blockIdx.x * NBUK_P + i] = hist[i];
}

// ---------------- phase 2: column scan over chunks; excT transposed ----------------

__global__ __launch_bounds__(256) void k_colscan(const int* __restrict__ bhist,
                                                 int* __restrict__ excT,
                                                 int* __restrict__ colsum) {
    __shared__ int part[256];
    int b = blockIdx.x;   // bucket
    int t = threadIdx.x;
    int v[4];
    int s = 0;
#pragma unroll
    for (int i = 0; i < 4; i++) {
        int blk = t * 4 + i;
        v[i] = (blk < NBLK) ? bhist[blk * NBUK_P + b] : 0;
        s += v[i];
    }
    part[t] = s;
    __syncthreads();
    for (int off = 1; off < 256; off <<= 1) {
        int p = (t >= off) ? part[t - off] : 0;
        __syncthreads();
        part[t] += p;
        __syncthreads();
    }
    int run = (t == 0) ? 0 : part[t - 1];
#pragma unroll
    for (int i = 0; i < 4; i++) {
        int blk = t * 4 + i;
        if (blk < NBLK) excT[b * NBLK_P + blk] = run;
        run += v[i];
    }
    if (t == 255) colsum[b] = run;
}

// ---------------- phase 3: scan 782 bucket totals -> bucket_off ----------------

__global__ __launch_bounds__(256) void k_bucket_scan(const int* __restrict__ colsum,
                                                     int* __restrict__ bucket_off,
                                                     int* __restrict__ row_ptr) {
    __shared__ int part[256];
    int t = threadIdx.x;
    int v[4];
    int s = 0;
#pragma unroll
    for (int i = 0; i < 4; i++) {
        int idx = t * 4 + i;
        v[i] = (idx < NBUK) ? colsum[idx] : 0;
        s += v[i];
    }
    part[t] = s;
    __syncthreads();
    for (int off = 1; off < 256; off <<= 1) {
        int p = (t >= off) ? part[t - off] : 0;
        __syncthreads();
        part[t] += p;
        __syncthreads();
    }
    int run = (t == 0) ? 0 : part[t - 1];
#pragma unroll
    for (int i = 0; i < 4; i++) {
        int idx = t * 4 + i;
        if (idx < NBUK) { bucket_off[idx] = run; run += v[i]; }
        else if (idx == NBUK) bucket_off[idx] = run;  // == N_EDGES
    }
    if (t == 0) row_ptr[N_NODES] = N_EDGES;
}

// ---------------- phase 4: deterministic scatter of packed records ----------------
// pk = (src << 7) | (dst & 63)

__global__ __launch_bounds__(256) void k_binA2(const int4* __restrict__ src4,
                                               const int4* __restrict__ dst4,
                                               const int* __restrict__ excT,
                                               const int* __restrict__ bucket_off,
                                               int* __restrict__ ebin) {
    __shared__ int cur[NBUK];
    int t = threadIdx.x;
    for (int i = t; i < NBUK; i += 256)
        cur[i] = bucket_off[i] + excT[i * NBLK_P + blockIdx.x];
    __syncthreads();
    int idx = blockIdx.x * 256 + t;
    if (idx < N_EDGES / 4) {
        int4 s = src4[idx];
        int4 d = dst4[idx];
        int p0 = atomicAdd(&cur[d.x >> 6], 1);
        int p1 = atomicAdd(&cur[d.y >> 6], 1);
        int p2 = atomicAdd(&cur[d.z >> 6], 1);
        int p3 = atomicAdd(&cur[d.w >> 6], 1);
        ebin[p0] = (s.x << 7) | (d.x & 63);
        ebin[p1] = (s.y << 7) | (d.y & 63);
        ebin[p2] = (s.z << 7) | (d.z & 63);
        ebin[p3] = (s.w << 7) | (d.w & 63);
    }
}

// ---------------- phase 5: per-bucket CSR: degree count + scan + node-sorted scatter ----------------
// All LDS-local; rec = src index only (weights folded into hs/zs).

__global__ __launch_bounds__(256) void k_bucket_csr(const int* __restrict__ ebin,
                                                    const int* __restrict__ bucket_off,
                                                    int* __restrict__ row_ptr,
                                                    float* __restrict__ dinv,
                                                    int* __restrict__ rec) {
    __shared__ int cnt[64];
    __shared__ int cur[64];
    int b = blockIdx.x;
    int t = threadIdx.x;
    if (t < 64) cnt[t] = 0;
    __syncthreads();
    int beg = bucket_off[b], end = bucket_off[b + 1];
    for (int i = beg + t; i < end; i += 256) atomicAdd(&cnt[ebin[i] & 63], 1);
    __syncthreads();
    if (t < 64) {
        int deg = cnt[t];
        int sum = deg;  // inclusive wave scan over 64 lanes
#pragma unroll
        for (int off = 1; off < 64; off <<= 1) {
            int v = __shfl_up(sum, off, 64);
            if (t >= off) sum += v;
        }
        int rp = beg + sum - deg;
        cur[t] = rp;
        int node = b * 64 + t;
        if (node < N_NODES) {
            row_ptr[node] = rp;
            dinv[node] = rsqrtf((float)(deg + 1));  // +1 self-loop
        }
    }
    __syncthreads();
    for (int i = beg + t; i < end; i += 256) {
        int pk = ebin[i];
        int pos = atomicAdd(&cur[pk & 63], 1);
        rec[pos] = pk >> 7;
    }
}

// ---------------- GEMM1: hs = (x @ W1) * dinv[row], fp16; rows >= N_NODES zeroed (pad row) ----------------

__device__ inline void fma4(float4& acc, float s, const float4& w) {
    acc.x = fmaf(s, w.x, acc.x);
    acc.y = fmaf(s, w.y, acc.y);
    acc.z = fmaf(s, w.z, acc.z);
    acc.w = fmaf(s, w.w, acc.w);
}

__global__ __launch_bounds__(256) void k_gemm1(
    const float* __restrict__ x, const float* __restrict__ W1,
    const float* __restrict__ dinv, _Float16* __restrict__ hs)
{
    __shared__ float Ws[D_IN * HIDDEN];  // 32KB
    __shared__ float xs[64 * D_IN];      // 32KB
    const int tid = threadIdx.x;
    const int row0 = blockIdx.x * 64;

    const float4* W4 = (const float4*)W1;
    float4* Ws4 = (float4*)Ws;
    for (int i = tid; i < D_IN * HIDDEN / 4; i += 256) Ws4[i] = W4[i];

    for (int i = tid; i < 64 * D_IN / 4; i += 256) {
        int r = i >> 5;
        int k4 = (i & 31) << 2;
        float4 v = make_float4(0.f, 0.f, 0.f, 0.f);
        int grow = row0 + r;
        if (grow < N_NODES) v = *(const float4*)&x[grow * D_IN + k4];
        int sw = ((r >> 2) & 1) << 4;
        *(float4*)&xs[r * D_IN + (k4 ^ sw)] = v;
    }
    __syncthreads();

    const int c4 = (tid & 15) * 4;
    const int r4 = (tid >> 4) * 4;
    float4 acc[4];
#pragma unroll
    for (int j = 0; j < 4; j++) acc[j] = make_float4(0.f, 0.f, 0.f, 0.f);

    for (int k = 0; k < D_IN; k += 4) {
        float4 w0 = *(const float4*)&Ws[(k + 0) * HIDDEN + c4];
        float4 w1 = *(const float4*)&Ws[(k + 1) * HIDDEN + c4];
        float4 w2 = *(const float4*)&Ws[(k + 2) * HIDDEN + c4];
        float4 w3 = *(const float4*)&Ws[(k + 3) * HIDDEN + c4];
        float4 a[4];
#pragma unroll
        for (int j = 0; j < 4; j++) {
            int r = r4 + j;
            int sw = ((r >> 2) & 1) << 4;
            a[j] = *(const float4*)&xs[r * D_IN + (k ^ sw)];
        }
#pragma unroll
        for (int j = 0; j < 4; j++) {
            fma4(acc[j], a[j].x, w0);
            fma4(acc[j], a[j].y, w1);
            fma4(acc[j], a[j].z, w2);
            fma4(acc[j], a[j].w, w3);
        }
    }

#pragma unroll
    for (int j = 0; j < 4; j++) {
        int grow = row0 + r4 + j;
        half4v hv;
        if (grow < N_NODES) {
            float di = dinv[grow];
            hv.x = (_Float16)(acc[j].x * di);
            hv.y = (_Float16)(acc[j].y * di);
            hv.z = (_Float16)(acc[j].z * di);
            hv.w = (_Float16)(acc[j].w * di);
        } else {
            hv.x = hv.y = hv.z = hv.w = (_Float16)0.f;  // pad row for dummy edges
        }
        *(half4v*)&hs[grow * HIDDEN + c4] = hv;
    }
}

// ---------------- fused agg1 + relu + layer2: wave per node (12500 blocks) ----------------
// a = di * (hs[node] + sum_nbr hs[src]); y = relu(a + b1); zs = (y@W2)*di

__global__ __launch_bounds__(256) void k_agg1_l2(
    const _Float16* __restrict__ hs, const int* __restrict__ row_ptr,
    const int* __restrict__ rec, const float* __restrict__ dinv,
    const float* __restrict__ b1, const float* __restrict__ W2,
    float* __restrict__ zs)
{
    int node = blockIdx.x * 4 + (threadIdx.x >> 6);  // grid 12500, exact
    int lane = threadIdx.x & 63;

    float di = dinv[node];
    float acc = (float)hs[node * HIDDEN + lane];  // self-loop (dinv[node] folded in hs)

    int beg = row_ptr[node];
    int end = row_ptr[node + 1];

    for (int base = beg; base < end; base += 64) {
        int n = end - base;
        if (n > 64) n = 64;
        int r = N_NODES;  // pad: zero row of hs
        if (lane < n) r = rec[base + lane];
        int n4 = (n + 3) & ~3;
        for (int e = 0; e < n4; e += 4) {
            int s0 = __shfl(r, e + 0, 64);
            int s1 = __shfl(r, e + 1, 64);
            int s2 = __shfl(r, e + 2, 64);
            int s3 = __shfl(r, e + 3, 64);
            float v0 = (float)hs[s0 * HIDDEN + lane];
            float v1 = (float)hs[s1 * HIDDEN + lane];
            float v2 = (float)hs[s2 * HIDDEN + lane];
            float v3 = (float)hs[s3 * HIDDEN + lane];
            acc += v0 + v1;
            acc += v2 + v3;
        }
    }
    acc *= di;

    float y = fmaxf(acc + b1[lane], 0.0f);
    float p0 = y * W2[lane * N_CLASSES + 0];
    float p1 = y * W2[lane * N_CLASSES + 1];
#pragma unroll
    for (int off = 32; off > 0; off >>= 1) {
        p0 += __shfl_down(p0, off, 64);
        p1 += __shfl_down(p1, off, 64);
    }
    if (lane == 0) {
        zs[node * 2 + 0] = p0 * di;  // pre-scaled for layer-2 aggregation
        zs[node * 2 + 1] = p1 * di;
    }
}

// ---------------- agg2: wave per node; out = b2 + di*(sum_nbr zs[src] + zs[node]) ----------------

__global__ __launch_bounds__(256) void k_agg2(
    const float* __restrict__ zs, const int* __restrict__ row_ptr,
    const int* __restrict__ rec, const float* __restrict__ dinv,
    const float* __restrict__ b2, float* __restrict__ out)
{
    int node = blockIdx.x * 4 + (threadIdx.x >> 6);  // grid 12500, exact
    int lane = threadIdx.x & 63;
    int beg = row_ptr[node];
    int end = row_ptr[node + 1];
    float a0 = 0.f, a1 = 0.f;
    for (int idx = beg + lane; idx < end; idx += 64) {
        int s = rec[idx];
        float2 v = *(const float2*)&zs[s * 2];
        a0 += v.x;
        a1 += v.y;
    }
#pragma unroll
    for (int off = 32; off > 0; off >>= 1) {
        a0 += __shfl_down(a0, off, 64);
        a1 += __shfl_down(a1, off, 64);
    }
    if (lane == 0) {
        float di = dinv[node];
        float2 zv = *(const float2*)&zs[node * 2];
        float2 o;
        o.x = fmaf(di, a0 + zv.x, b2[0]);
        o.y = fmaf(di, a1 + zv.y, b2[1]);
        *(float2*)&out[node * 2] = o;
    }
}

// ---------------- launch ----------------

extern "C" void kernel_launch(void* const* d_in, const int* in_sizes, int n_in,
                              void* d_out, int out_size, void* d_ws, size_t ws_size,
                              hipStream_t stream) {
    const float* x  = (const float*)d_in[0];
    const int* ei   = (const int*)d_in[1];
    const float* W1 = (const float*)d_in[2];
    const float* b1 = (const float*)d_in[3];
    const float* W2 = (const float*)d_in[4];
    const float* b2 = (const float*)d_in[5];
    float* out = (float*)d_out;

    const int* src = ei;
    const int* dst = ei + N_EDGES;

    // workspace layout (4-byte units), ~18.5 MB
    int*      bucket_off = (int*)d_ws;                   // [0, 1024)       783 used
    int*      colsum     = (int*)d_ws + 1024;            // [1024, 2048)
    float*    dinv       = (float*)d_ws + 2048;          // [2048, 52224)
    int*      row_ptr    = (int*)d_ws + 52224;           // 50001 -> pad to 102432
    int*      bhist      = (int*)d_ws + 102432;          // 782*784 -> pad 613120
    int*      excT       = (int*)d_ws + 715552;          // 782*784 -> pad 613120
    int*      ebin       = (int*)d_ws + 1328672;         // 800000 packed ints
    int*      rec        = (int*)d_ws + 2128672;         // 800000 src ints
    _Float16* hs         = (_Float16*)((int*)d_ws + 2928672);  // 50048*64 halves (128B aligned)
    float*    zs         = (float*)d_ws + 4530208;       // 100000 floats

    k_hist<<<NBLK, 256, 0, stream>>>((const int4*)dst, bhist);
    k_colscan<<<NBUK, 256, 0, stream>>>(bhist, excT, colsum);
    k_bucket_scan<<<1, 256, 0, stream>>>(colsum, bucket_off, row_ptr);
    k_binA2<<<NBLK, 256, 0, stream>>>((const int4*)src, (const int4*)dst, excT, bucket_off, ebin);
    k_bucket_csr<<<NBUK, 256, 0, stream>>>(ebin, bucket_off, row_ptr, dinv, rec);
    k_gemm1<<<(N_NODES + 63) / 64, 256, 0, stream>>>(x, W1, dinv, hs);
    k_agg1_l2<<<N_NODES / 4, 256, 0, stream>>>(hs, row_ptr, rec, dinv, b1, W2, zs);
    k_agg2<<<N_NODES / 4, 256, 0, stream>>>(zs, row_ptr, rec, dinv, b2, out);
}